// Round 4
// baseline (255.812 us; speedup 1.0000x reference)
//
#include <hip/hip_runtime.h>
#include <hip/hip_bf16.h>

#define D_DIM 256
#define H_DIM 128
#define R_DIM 4

typedef __bf16 bf16x8 __attribute__((ext_vector_type(8)));
typedef float f32x4 __attribute__((ext_vector_type(4)));

__device__ __forceinline__ unsigned short f2bf(float f) {
    union { float f; unsigned u; } v; v.f = f;
    unsigned r = (v.u + 0x7FFFu + ((v.u >> 16) & 1u)) >> 16;   // RNE
    return (unsigned short)r;
}

// ---------------- x (N,256) fp32 -> bf16
__global__ void xcvt_kernel(const float* __restrict__ x, unsigned short* __restrict__ xb, int total8) {
    int i = blockIdx.x * blockDim.x + threadIdx.x;
    int stride = gridDim.x * blockDim.x;
    for (; i < total8; i += stride) {
        const float4* xp = (const float4*)(x + (size_t)i * 8);
        float4 v0 = xp[0], v1 = xp[1];
        uint4 o;
        o.x = (unsigned)f2bf(v0.x) | ((unsigned)f2bf(v0.y) << 16);
        o.y = (unsigned)f2bf(v0.z) | ((unsigned)f2bf(v0.w) << 16);
        o.z = (unsigned)f2bf(v1.x) | ((unsigned)f2bf(v1.y) << 16);
        o.w = (unsigned)f2bf(v1.z) | ((unsigned)f2bf(v1.w) << 16);
        *(uint4*)(xb + (size_t)i * 8) = o;
    }
}

// ---------------- W (R,256,128) fp32 -> Wt (R,128,256) bf16 (transposed, K-contiguous)
__global__ void wtcvt_kernel(const float* __restrict__ W, unsigned short* __restrict__ Wt) {
    int idx = blockIdx.x * blockDim.x + threadIdx.x;
    if (idx >= R_DIM * D_DIM * H_DIM) return;
    int d = idx & 255;
    int h = (idx >> 8) & 127;
    int r = idx >> 15;
    Wt[idx] = f2bf(W[((size_t)(r * D_DIM + d)) * H_DIM + h]);
}

// ---------------- K_v: v1[r][d] = sum_h W[r][d][h]*a1[h]; v2 with a2; c1[r]=b[r].a1, c2[r]=b[r].a2
__global__ void kv_kernel(const float* __restrict__ W, const float* __restrict__ b,
                          const float* __restrict__ a,
                          float* __restrict__ v1, float* __restrict__ v2,
                          float* __restrict__ c1, float* __restrict__ c2) {
    int t = blockIdx.x * blockDim.x + threadIdx.x;
    if (t < R_DIM * D_DIM) {
        int r = t >> 8;
        int d = t & 255;
        const float* wp = W + ((size_t)r * D_DIM + d) * H_DIM;
        float acc1 = 0.f, acc2 = 0.f;
        for (int h = 0; h < H_DIM; ++h) {
            float w = wp[h];
            acc1 += w * a[h];
            acc2 += w * a[H_DIM + h];
        }
        v1[t] = acc1; v2[t] = acc2;
    }
    if (t < R_DIM) {
        const float* bp = b + t * H_DIM;
        float acc1 = 0.f, acc2 = 0.f;
        for (int h = 0; h < H_DIM; ++h) {
            acc1 += bp[h] * a[h];
            acc2 += bp[h] * a[H_DIM + h];
        }
        c1[t] = acc1; c2[t] = acc2;
    }
}

// ---------------- K_s: s1[r*N+n] = x[n].v1[r] + c1[r]; s2 likewise (exact fp32 path)
__global__ void ks_kernel(const float* __restrict__ x,
                          const float* __restrict__ v1, const float* __restrict__ v2,
                          const float* __restrict__ c1, const float* __restrict__ c2,
                          float* __restrict__ s1, float* __restrict__ s2, int N) {
    __shared__ float sv1[R_DIM * D_DIM];
    __shared__ float sv2[R_DIM * D_DIM];
    for (int i = threadIdx.x; i < R_DIM * D_DIM; i += blockDim.x) {
        sv1[i] = v1[i]; sv2[i] = v2[i];
    }
    __syncthreads();
    int n = blockIdx.x * blockDim.x + threadIdx.x;
    if (n >= N) return;
    float a1[R_DIM] = {0.f, 0.f, 0.f, 0.f};
    float a2[R_DIM] = {0.f, 0.f, 0.f, 0.f};
    const float4* xp = (const float4*)(x + (size_t)n * D_DIM);
    for (int d4 = 0; d4 < D_DIM / 4; ++d4) {
        float4 xv = xp[d4];
        #pragma unroll
        for (int r = 0; r < R_DIM; ++r) {
            float4 w1 = *(const float4*)&sv1[r * D_DIM + d4 * 4];
            float4 w2 = *(const float4*)&sv2[r * D_DIM + d4 * 4];
            a1[r] += xv.x * w1.x + xv.y * w1.y + xv.z * w1.z + xv.w * w1.w;
            a2[r] += xv.x * w2.x + xv.y * w2.y + xv.z * w2.z + xv.w * w2.w;
        }
    }
    #pragma unroll
    for (int r = 0; r < R_DIM; ++r) {
        s1[(size_t)r * N + n] = a1[r] + c1[r];
        s2[(size_t)r * N + n] = a2[r] + c2[r];
    }
}

// ---------------- Direct-from-cache MFMA GEMM (no LDS, no barriers)
// Hall[r][n][h] = bf16( xb[n,:] . Wt[r][h,:] + b[r][h] )
// Block = 256 thr = 4 waves (2x2); wave tile 64x64; K pipelined 2-deep in regs.
__global__ void __launch_bounds__(256)
gemm_mfma2_kernel(const unsigned short* __restrict__ xb, const unsigned short* __restrict__ Wt,
                  const float* __restrict__ bias, __hip_bfloat16* __restrict__ Hall, int N) {
    const int t = threadIdx.x;
    const int lane = t & 63;
    const int w = t >> 6;
    const int wm = w >> 1, wn = w & 1;
    const int r = blockIdx.y;
    const int l15 = lane & 15;
    const int kO = (lane >> 4) * 8;                 // k sub-offset (elements)
    const int rowW = blockIdx.x * 128 + wm * 64;    // wave row base
    const int colW = wn * 64;                       // wave col base

    // per-lane fragment base pointers (A: row-major xb; B: Wt K-contiguous)
    const unsigned short* Ap[4];
    const unsigned short* Bp[4];
    #pragma unroll
    for (int mf = 0; mf < 4; ++mf) {
        int rr = rowW + mf * 16 + l15;
        if (rr >= N) rr = N - 1;                    // clamp; stores are guarded
        Ap[mf] = xb + (size_t)rr * D_DIM + kO;
    }
    #pragma unroll
    for (int nf = 0; nf < 4; ++nf) {
        int cc = colW + nf * 16 + l15;
        Bp[nf] = Wt + ((size_t)r * H_DIM + cc) * D_DIM + kO;
    }

    f32x4 acc[4][4];
    #pragma unroll
    for (int i = 0; i < 4; ++i)
        #pragma unroll
        for (int j = 0; j < 4; ++j)
            acc[i][j] = (f32x4){0.f, 0.f, 0.f, 0.f};

    // 2-deep software pipeline over 8 K-steps (K=32 each), even/odd reg sets
    bf16x8 aE[4], bE[4], aO[4], bO[4];
    #pragma unroll
    for (int mf = 0; mf < 4; ++mf) aE[mf] = *(const bf16x8*)(Ap[mf]);
    #pragma unroll
    for (int nf = 0; nf < 4; ++nf) bE[nf] = *(const bf16x8*)(Bp[nf]);

    #pragma unroll
    for (int ks = 0; ks < 8; ks += 2) {
        if (ks + 1 < 8) {   // prefetch odd step
            #pragma unroll
            for (int mf = 0; mf < 4; ++mf) aO[mf] = *(const bf16x8*)(Ap[mf] + (ks + 1) * 32);
            #pragma unroll
            for (int nf = 0; nf < 4; ++nf) bO[nf] = *(const bf16x8*)(Bp[nf] + (ks + 1) * 32);
        }
        #pragma unroll
        for (int mf = 0; mf < 4; ++mf)
            #pragma unroll
            for (int nf = 0; nf < 4; ++nf)
                acc[mf][nf] = __builtin_amdgcn_mfma_f32_16x16x32_bf16(aE[mf], bE[nf], acc[mf][nf], 0, 0, 0);
        if (ks + 2 < 8) {   // prefetch next even step
            #pragma unroll
            for (int mf = 0; mf < 4; ++mf) aE[mf] = *(const bf16x8*)(Ap[mf] + (ks + 2) * 32);
            #pragma unroll
            for (int nf = 0; nf < 4; ++nf) bE[nf] = *(const bf16x8*)(Bp[nf] + (ks + 2) * 32);
        }
        if (ks + 1 < 8) {
            #pragma unroll
            for (int mf = 0; mf < 4; ++mf)
                #pragma unroll
                for (int nf = 0; nf < 4; ++nf)
                    acc[mf][nf] = __builtin_amdgcn_mfma_f32_16x16x32_bf16(aO[mf], bO[nf], acc[mf][nf], 0, 0, 0);
        }
    }

    // ---- epilogue: C/D layout col=lane&15, row=(lane>>4)*4+j
    #pragma unroll
    for (int nf = 0; nf < 4; ++nf) {
        int col = colW + nf * 16 + l15;
        float bv = bias[r * H_DIM + col];
        #pragma unroll
        for (int mf = 0; mf < 4; ++mf) {
            int rowb = rowW + mf * 16 + (lane >> 4) * 4;
            #pragma unroll
            for (int j = 0; j < 4; ++j) {
                int gr = rowb + j;
                if (gr < N) {
                    float val = acc[mf][nf][j] + bv;
                    Hall[((size_t)r * N + gr) * H_DIM + col] = __float2bfloat16(val);
                }
            }
        }
    }
}

// ---------------- per-edge scores + per-row slot assignment
__global__ void kscore_kernel(const int* __restrict__ eidx, const int* __restrict__ etype,
                              const float* __restrict__ s1, const float* __restrict__ s2,
                              float* __restrict__ escore, int* __restrict__ slot,
                              int* __restrict__ cnt, int N, int E) {
    int e = blockIdx.x * blockDim.x + threadIdx.x;
    if (e >= E) return;
    int row = eidx[e];
    int col = eidx[E + e];
    int r = etype[e];
    float sc = s1[(size_t)r * N + row] + s2[(size_t)r * N + col];
    sc = (sc >= 0.f) ? sc : 0.2f * sc;
    escore[e] = sc;
    slot[e] = atomicAdd(&cnt[row], 1);
}

// ---------------- segment allocation (unordered, contiguous per row)
__global__ void kalloc_kernel(const int* __restrict__ cnt, int* __restrict__ ofs,
                              int* __restrict__ counter, int N) {
    int n = blockIdx.x * blockDim.x + threadIdx.x;
    if (n < N) ofs[n] = atomicAdd(counter, cnt[n]);
}

// ---------------- place perm-ordered edge records: packed offset + score
__global__ void kplace2_kernel(const int* __restrict__ eidx, const int* __restrict__ etype,
                               const float* __restrict__ escore,
                               const int* __restrict__ ofs, const int* __restrict__ slot,
                               unsigned* __restrict__ poff, float* __restrict__ pscore,
                               int N, int E) {
    int e = blockIdx.x * blockDim.x + threadIdx.x;
    if (e >= E) return;
    int row = eidx[e];
    int col = eidx[E + e];
    int r = etype[e];
    int pos = ofs[row] + slot[e];
    poff[pos] = (((unsigned)(r * N + col)) << 2) | (unsigned)r;
    pscore[pos] = escore[e];
}

// ---------------- 4 rows per block (one wave each): in-register softmax + gather
__global__ void __launch_bounds__(256)
krow2_kernel(const unsigned* __restrict__ poff, const float* __restrict__ pscore,
             const int* __restrict__ ofs, const int* __restrict__ cnt,
             const __hip_bfloat16* __restrict__ Hall,
             float* __restrict__ out, int N) {
    const int wave = threadIdx.x >> 6;
    const int lane = threadIdx.x & 63;
    const int n = blockIdx.x * 4 + wave;
    if (n >= N) return;
    const int start = ofs[n];
    const int deg = cnt[n];

    float acc0 = 0.f, acc1 = 0.f;

    if (deg <= 64) {
        float sc = -1e30f;
        unsigned u = 0u;
        int r_i = 0;
        if (lane < deg) {
            u = poff[start + lane];
            sc = pscore[start + lane];
            r_i = (int)(u & 3u);
        }
        float m0, m1, m2, m3;
        {
            float v0 = (r_i == 0 && lane < deg) ? sc : -1e30f;
            float v1 = (r_i == 1 && lane < deg) ? sc : -1e30f;
            float v2 = (r_i == 2 && lane < deg) ? sc : -1e30f;
            float v3 = (r_i == 3 && lane < deg) ? sc : -1e30f;
            #pragma unroll
            for (int o = 32; o > 0; o >>= 1) {
                v0 = fmaxf(v0, __shfl_xor(v0, o));
                v1 = fmaxf(v1, __shfl_xor(v1, o));
                v2 = fmaxf(v2, __shfl_xor(v2, o));
                v3 = fmaxf(v3, __shfl_xor(v3, o));
            }
            m0 = v0; m1 = v1; m2 = v2; m3 = v3;
        }
        float m_i = (r_i == 0) ? m0 : ((r_i == 1) ? m1 : ((r_i == 2) ? m2 : m3));
        float wgt = (lane < deg) ? __expf(sc - m_i) : 0.f;
        float s0, s1, s2, s3;
        {
            float v0 = (r_i == 0) ? wgt : 0.f;
            float v1 = (r_i == 1) ? wgt : 0.f;
            float v2 = (r_i == 2) ? wgt : 0.f;
            float v3 = (r_i == 3) ? wgt : 0.f;
            #pragma unroll
            for (int o = 32; o > 0; o >>= 1) {
                v0 += __shfl_xor(v0, o);
                v1 += __shfl_xor(v1, o);
                v2 += __shfl_xor(v2, o);
                v3 += __shfl_xor(v3, o);
            }
            s0 = v0; s1 = v1; s2 = v2; s3 = v3;
        }
        float s_i = (r_i == 0) ? s0 : ((r_i == 1) ? s1 : ((r_i == 2) ? s2 : s3));
        float alpha = (lane < deg && s_i > 0.f) ? (wgt / s_i) : 0.f;

        for (int j = 0; j < deg; j += 4) {
            #pragma unroll
            for (int jj = 0; jj < 4; ++jj) {
                int idx = j + jj;
                float al = __shfl(alpha, idx);
                int uj = __shfl((int)u, idx);
                if (idx < deg) {
                    const __hip_bfloat16* hp = Hall + (size_t)(((unsigned)uj) >> 2) * H_DIM;
                    acc0 += al * __bfloat162float(hp[lane]);
                    acc1 += al * __bfloat162float(hp[lane + 64]);
                }
            }
        }
    } else {
        float v0 = -1e30f, v1 = -1e30f, v2 = -1e30f, v3 = -1e30f;
        for (int i = lane; i < deg; i += 64) {
            unsigned u = poff[start + i];
            float sc = pscore[start + i];
            int r = (int)(u & 3u);
            if (r == 0) v0 = fmaxf(v0, sc);
            else if (r == 1) v1 = fmaxf(v1, sc);
            else if (r == 2) v2 = fmaxf(v2, sc);
            else v3 = fmaxf(v3, sc);
        }
        #pragma unroll
        for (int o = 32; o > 0; o >>= 1) {
            v0 = fmaxf(v0, __shfl_xor(v0, o));
            v1 = fmaxf(v1, __shfl_xor(v1, o));
            v2 = fmaxf(v2, __shfl_xor(v2, o));
            v3 = fmaxf(v3, __shfl_xor(v3, o));
        }
        const float m0 = v0, m1 = v1, m2 = v2, m3 = v3;
        float t0 = 0.f, t1 = 0.f, t2 = 0.f, t3 = 0.f;
        for (int i = lane; i < deg; i += 64) {
            unsigned u = poff[start + i];
            float sc = pscore[start + i];
            int r = (int)(u & 3u);
            if (r == 0) t0 += __expf(sc - m0);
            else if (r == 1) t1 += __expf(sc - m1);
            else if (r == 2) t2 += __expf(sc - m2);
            else t3 += __expf(sc - m3);
        }
        #pragma unroll
        for (int o = 32; o > 0; o >>= 1) {
            t0 += __shfl_xor(t0, o);
            t1 += __shfl_xor(t1, o);
            t2 += __shfl_xor(t2, o);
            t3 += __shfl_xor(t3, o);
        }
        float i0 = (t0 > 0.f) ? 1.f / t0 : 0.f;
        float i1 = (t1 > 0.f) ? 1.f / t1 : 0.f;
        float i2 = (t2 > 0.f) ? 1.f / t2 : 0.f;
        float i3 = (t3 > 0.f) ? 1.f / t3 : 0.f;
        for (int i = 0; i < deg; ++i) {
            unsigned u = poff[start + i];
            float sc = pscore[start + i];
            int r = (int)(u & 3u);
            float m_r = (r == 0) ? m0 : ((r == 1) ? m1 : ((r == 2) ? m2 : m3));
            float inv = (r == 0) ? i0 : ((r == 1) ? i1 : ((r == 2) ? i2 : i3));
            float al = __expf(sc - m_r) * inv;
            const __hip_bfloat16* hp = Hall + (size_t)(u >> 2) * H_DIM;
            acc0 += al * __bfloat162float(hp[lane]);
            acc1 += al * __bfloat162float(hp[lane + 64]);
        }
    }

    out[(size_t)n * H_DIM + lane] = acc0;
    out[(size_t)n * H_DIM + 64 + lane] = acc1;
}

// ---------------- launch
static inline char* carve(char*& p, size_t bytes) {
    char* q = p;
    p += (bytes + 255) & ~(size_t)255;
    return q;
}

extern "C" void kernel_launch(void* const* d_in, const int* in_sizes, int n_in,
                              void* d_out, int out_size, void* d_ws, size_t ws_size,
                              hipStream_t stream) {
    const float* x     = (const float*)d_in[0];
    const int*   eidx  = (const int*)d_in[1];
    const int*   etype = (const int*)d_in[2];
    const float* a     = (const float*)d_in[3];
    const float* W     = (const float*)d_in[4];
    const float* b     = (const float*)d_in[5];
    float* out = (float*)d_out;

    const int E = in_sizes[2];
    const int N = in_sizes[0] / D_DIM;

    char* p = (char*)d_ws;
    __hip_bfloat16* Hall = (__hip_bfloat16*)carve(p, (size_t)R_DIM * N * H_DIM * 2);
    unsigned short* xb   = (unsigned short*)carve(p, (size_t)N * D_DIM * 2);
    unsigned short* Wt   = (unsigned short*)carve(p, (size_t)R_DIM * D_DIM * H_DIM * 2);
    float* s1     = (float*)carve(p, (size_t)R_DIM * N * 4);
    float* s2     = (float*)carve(p, (size_t)R_DIM * N * 4);
    float* v1     = (float*)carve(p, R_DIM * D_DIM * 4);
    float* v2     = (float*)carve(p, R_DIM * D_DIM * 4);
    float* c1     = (float*)carve(p, 64);
    float* c2     = (float*)carve(p, 64);
    float* escore = (float*)carve(p, (size_t)E * 4);
    int*   slot   = (int*)carve(p, (size_t)E * 4);
    unsigned* poff   = (unsigned*)carve(p, (size_t)E * 4);
    float*    pscore = (float*)carve(p, (size_t)E * 4);
    int*   ofs    = (int*)carve(p, (size_t)N * 4);
    int*   cnt    = (int*)carve(p, (size_t)N * 4 + 4);   // counter lives at cnt[N]
    int*   counter = cnt + N;

    hipMemsetAsync(cnt, 0, (size_t)N * 4 + 4, stream);

    kv_kernel<<<4, 256, 0, stream>>>(W, b, a, v1, v2, c1, c2);
    ks_kernel<<<(N + 255) / 256, 256, 0, stream>>>(x, v1, v2, c1, c2, s1, s2, N);
    xcvt_kernel<<<2048, 256, 0, stream>>>(x, xb, N * D_DIM / 8);
    wtcvt_kernel<<<(R_DIM * D_DIM * H_DIM + 255) / 256, 256, 0, stream>>>(W, Wt);
    gemm_mfma2_kernel<<<dim3((N + 127) / 128, R_DIM), 256, 0, stream>>>(xb, Wt, b, Hall, N);
    kscore_kernel<<<(E + 255) / 256, 256, 0, stream>>>(eidx, etype, s1, s2, escore, slot, cnt, N, E);
    kalloc_kernel<<<(N + 255) / 256, 256, 0, stream>>>(cnt, ofs, counter, N);
    kplace2_kernel<<<(E + 255) / 256, 256, 0, stream>>>(eidx, etype, escore, ofs, slot, poff, pscore, N, E);
    krow2_kernel<<<(N + 3) / 4, 256, 0, stream>>>(poff, pscore, ofs, cnt, Hall, out, N);
}

// Round 5
// 211.758 us; speedup vs baseline: 1.2080x; 1.2080x over previous
//
#include <hip/hip_runtime.h>
#include <hip/hip_bf16.h>

#define D_DIM 256
#define H_DIM 128
#define R_DIM 4

typedef __bf16 bf16x8 __attribute__((ext_vector_type(8)));
typedef float f32x4 __attribute__((ext_vector_type(4)));

__device__ __forceinline__ unsigned short f2bf(float f) {
    union { float f; unsigned u; } v; v.f = f;
    unsigned r = (v.u + 0x7FFFu + ((v.u >> 16) & 1u)) >> 16;   // RNE
    return (unsigned short)r;
}

// ---------------- K_v: v1[r][d] = sum_h W[r][d][h]*a1[h]; v2 with a2; c1[r]=b[r].a1, c2[r]=b[r].a2
__global__ void kv_kernel(const float* __restrict__ W, const float* __restrict__ b,
                          const float* __restrict__ a,
                          float* __restrict__ v1, float* __restrict__ v2,
                          float* __restrict__ c1, float* __restrict__ c2) {
    int t = blockIdx.x * blockDim.x + threadIdx.x;
    if (t < R_DIM * D_DIM) {
        int r = t >> 8;
        int d = t & 255;
        const float* wp = W + ((size_t)r * D_DIM + d) * H_DIM;
        float acc1 = 0.f, acc2 = 0.f;
        for (int h = 0; h < H_DIM; ++h) {
            float w = wp[h];
            acc1 += w * a[h];
            acc2 += w * a[H_DIM + h];
        }
        v1[t] = acc1; v2[t] = acc2;
    }
    if (t < R_DIM) {
        const float* bp = b + t * H_DIM;
        float acc1 = 0.f, acc2 = 0.f;
        for (int h = 0; h < H_DIM; ++h) {
            acc1 += bp[h] * a[h];
            acc2 += bp[h] * a[H_DIM + h];
        }
        c1[t] = acc1; c2[t] = acc2;
    }
}

// ---------------- W (R,256,128) fp32 -> Wt (R,128,256) bf16 (transposed, K-contiguous)
__global__ void wtcvt_kernel(const float* __restrict__ W, unsigned short* __restrict__ Wt) {
    int idx = blockIdx.x * blockDim.x + threadIdx.x;
    if (idx >= R_DIM * D_DIM * H_DIM) return;
    int d = idx & 255;
    int h = (idx >> 8) & 127;
    int r = idx >> 15;
    Wt[idx] = f2bf(W[((size_t)(r * D_DIM + d)) * H_DIM + h]);
}

// ---------------- ks2: fused scores + x->bf16. One wave per row (coalesced 1KB row read).
__global__ void __launch_bounds__(512)
ks2_kernel(const float* __restrict__ x,
           const float* __restrict__ v1, const float* __restrict__ v2,
           const float* __restrict__ c1, const float* __restrict__ c2,
           float* __restrict__ s1, float* __restrict__ s2,
           unsigned short* __restrict__ xb, int N) {
    __shared__ float sv1[R_DIM * D_DIM];
    __shared__ float sv2[R_DIM * D_DIM];
    __shared__ float sc[8];
    const int t = threadIdx.x;
    for (int i = t; i < R_DIM * D_DIM; i += 512) { sv1[i] = v1[i]; sv2[i] = v2[i]; }
    if (t < 4) { sc[t] = c1[t]; sc[4 + t] = c2[t]; }
    __syncthreads();
    const int wave = t >> 6, lane = t & 63;
    const int n = blockIdx.x * 8 + wave;
    if (n >= N) return;
    float4 xv = *(const float4*)(x + (size_t)n * D_DIM + lane * 4);
    // xb store (4 bf16 = 8B per lane, coalesced)
    unsigned lo = (unsigned)f2bf(xv.x) | ((unsigned)f2bf(xv.y) << 16);
    unsigned hi = (unsigned)f2bf(xv.z) | ((unsigned)f2bf(xv.w) << 16);
    *(uint2*)(xb + (size_t)n * D_DIM + lane * 4) = make_uint2(lo, hi);
    // 8 dot partials
    float d0, d1, d2, d3, d4, d5, d6, d7;
    {
        float4 w;
        w = *(const float4*)&sv1[0 * D_DIM + lane * 4]; d0 = xv.x*w.x + xv.y*w.y + xv.z*w.z + xv.w*w.w;
        w = *(const float4*)&sv1[1 * D_DIM + lane * 4]; d1 = xv.x*w.x + xv.y*w.y + xv.z*w.z + xv.w*w.w;
        w = *(const float4*)&sv1[2 * D_DIM + lane * 4]; d2 = xv.x*w.x + xv.y*w.y + xv.z*w.z + xv.w*w.w;
        w = *(const float4*)&sv1[3 * D_DIM + lane * 4]; d3 = xv.x*w.x + xv.y*w.y + xv.z*w.z + xv.w*w.w;
        w = *(const float4*)&sv2[0 * D_DIM + lane * 4]; d4 = xv.x*w.x + xv.y*w.y + xv.z*w.z + xv.w*w.w;
        w = *(const float4*)&sv2[1 * D_DIM + lane * 4]; d5 = xv.x*w.x + xv.y*w.y + xv.z*w.z + xv.w*w.w;
        w = *(const float4*)&sv2[2 * D_DIM + lane * 4]; d6 = xv.x*w.x + xv.y*w.y + xv.z*w.z + xv.w*w.w;
        w = *(const float4*)&sv2[3 * D_DIM + lane * 4]; d7 = xv.x*w.x + xv.y*w.y + xv.z*w.z + xv.w*w.w;
    }
    #pragma unroll
    for (int o = 32; o > 0; o >>= 1) {
        d0 += __shfl_xor(d0, o); d1 += __shfl_xor(d1, o);
        d2 += __shfl_xor(d2, o); d3 += __shfl_xor(d3, o);
        d4 += __shfl_xor(d4, o); d5 += __shfl_xor(d5, o);
        d6 += __shfl_xor(d6, o); d7 += __shfl_xor(d7, o);
    }
    if (lane == 0) {
        s1[(size_t)0 * N + n] = d0 + sc[0];
        s1[(size_t)1 * N + n] = d1 + sc[1];
        s1[(size_t)2 * N + n] = d2 + sc[2];
        s1[(size_t)3 * N + n] = d3 + sc[3];
        s2[(size_t)0 * N + n] = d4 + sc[4];
        s2[(size_t)1 * N + n] = d5 + sc[5];
        s2[(size_t)2 * N + n] = d6 + sc[6];
        s2[(size_t)3 * N + n] = d7 + sc[7];
    }
}

// ---------------- MFMA GEMM v3: one block = 128 rows x ALL 4 relations, K=256.
// A (xb tile 128x256 bf16 = 64KB) staged once, XOR-swizzled.
// B (Wt) streamed in 8KB chunks (BK=32) through 2 LDS slots, reg-prefetched 1 ahead.
// Swapped operands: mfma(Wt_frag, xb_frag, acc) -> D rows=h, cols=n -> 8B packed stores.
#define A_BYTES (128 * 512)
#define BSLOT_BYTES (128 * 64)
__global__ void __launch_bounds__(512)
gemm_mfma3_kernel(const unsigned short* __restrict__ xb, const unsigned short* __restrict__ Wt,
                  const float* __restrict__ bias, __hip_bfloat16* __restrict__ Hall, int N) {
    __shared__ __align__(16) char lds[A_BYTES + 2 * BSLOT_BYTES];   // 80 KB

    const int t = threadIdx.x;
    const int lane = t & 63;
    const int w = t >> 6;
    const int wm = w >> 2;          // 0..1 : n-half (64 rows)
    const int wn = w & 3;           // 0..3 : h-slice (32 cols)
    const int q = lane >> 4;        // k-quarter
    const int l15 = lane & 15;
    const int nBase = blockIdx.x * 128;
    const int hB = t >> 2, hCh = t & 3;   // B staging coords (thread -> (h, 16B chunk))

    // ---- prologue: load A tile + B chunk 0 to regs, then LDS (swizzled), barrier
    uint4 aR[8];
    #pragma unroll
    for (int i = 0; i < 8; ++i) {
        int idx = i * 512 + t;
        int n = idx >> 5, ch = idx & 31;
        int gn = nBase + n; if (gn >= N) gn = N - 1;
        aR[i] = *(const uint4*)(xb + (size_t)gn * D_DIM + ch * 8);
    }
    uint4 bR = *(const uint4*)(Wt + (size_t)hB * D_DIM + hCh * 8);   // r=0, k-chunk 0
    #pragma unroll
    for (int i = 0; i < 8; ++i) {
        int idx = i * 512 + t;
        int n = idx >> 5, ch = idx & 31;
        *(uint4*)(lds + n * 512 + ((ch ^ (n & 7)) << 4)) = aR[i];
    }
    *(uint4*)(lds + A_BYTES + hB * 64 + ((hCh ^ ((hB >> 1) & 3)) << 4)) = bR;
    __syncthreads();

    f32x4 acc[2][4];
    {   // acc init r=0 from bias
        #pragma unroll
        for (int hf = 0; hf < 2; ++hf) {
            f32x4 bv = *(const f32x4*)(bias + 0 * H_DIM + wn * 32 + hf * 16 + q * 4);
            #pragma unroll
            for (int nf = 0; nf < 4; ++nf) acc[hf][nf] = bv;
        }
    }

    int cur = 0;
    #pragma unroll 1
    for (int c = 0; c < 32; ++c) {
        const int r = c >> 3;
        uint4 nb;
        if (c < 31) {   // prefetch next chunk to regs
            int cn = c + 1;
            nb = *(const uint4*)(Wt + ((size_t)((cn >> 3) * H_DIM + hB)) * D_DIM + (cn & 7) * 32 + hCh * 8);
        }
        // fragments from LDS (swizzled reads)
        bf16x8 wf[2], xf[4];
        #pragma unroll
        for (int hf = 0; hf < 2; ++hf) {
            int hl = wn * 32 + hf * 16 + l15;
            wf[hf] = *(const bf16x8*)(lds + A_BYTES + (cur ? BSLOT_BYTES : 0) + hl * 64 + ((q ^ ((hl >> 1) & 3)) << 4));
        }
        #pragma unroll
        for (int nf = 0; nf < 4; ++nf) {
            int nl = wm * 64 + nf * 16 + l15;
            int sA = ((c & 7) << 2) | q;
            xf[nf] = *(const bf16x8*)(lds + nl * 512 + ((sA ^ (nl & 7)) << 4));
        }
        #pragma unroll
        for (int hf = 0; hf < 2; ++hf)
            #pragma unroll
            for (int nf = 0; nf < 4; ++nf)
                acc[hf][nf] = __builtin_amdgcn_mfma_f32_16x16x32_bf16(wf[hf], xf[nf], acc[hf][nf], 0, 0, 0);
        if (c < 31)
            *(uint4*)(lds + A_BYTES + (cur ? 0 : BSLOT_BYTES) + hB * 64 + ((hCh ^ ((hB >> 1) & 3)) << 4)) = nb;
        __syncthreads();
        cur ^= 1;
        if ((c & 7) == 7) {
            // store relation r tile: lane's 4 acc floats = 4 consecutive h -> 8B store
            #pragma unroll
            for (int hf = 0; hf < 2; ++hf) {
                int h = wn * 32 + hf * 16 + q * 4;
                #pragma unroll
                for (int nf = 0; nf < 4; ++nf) {
                    int n = nBase + wm * 64 + nf * 16 + l15;
                    if (n < N) {
                        unsigned lo = (unsigned)f2bf(acc[hf][nf][0]) | ((unsigned)f2bf(acc[hf][nf][1]) << 16);
                        unsigned hi = (unsigned)f2bf(acc[hf][nf][2]) | ((unsigned)f2bf(acc[hf][nf][3]) << 16);
                        *(uint2*)((unsigned short*)Hall + ((size_t)r * N + n) * H_DIM + h) = make_uint2(lo, hi);
                    }
                }
            }
            if (c < 31) {   // acc init for r+1
                #pragma unroll
                for (int hf = 0; hf < 2; ++hf) {
                    f32x4 bv = *(const f32x4*)(bias + (r + 1) * H_DIM + wn * 32 + hf * 16 + q * 4);
                    #pragma unroll
                    for (int nf = 0; nf < 4; ++nf) acc[hf][nf] = bv;
                }
            }
        }
    }
}

// ---------------- per-edge scores + per-row slot assignment
__global__ void kscore_kernel(const int* __restrict__ eidx, const int* __restrict__ etype,
                              const float* __restrict__ s1, const float* __restrict__ s2,
                              float* __restrict__ escore, int* __restrict__ slot,
                              int* __restrict__ cnt, int N, int E) {
    int e = blockIdx.x * blockDim.x + threadIdx.x;
    if (e >= E) return;
    int row = eidx[e];
    int col = eidx[E + e];
    int r = etype[e];
    float sc = s1[(size_t)r * N + row] + s2[(size_t)r * N + col];
    sc = (sc >= 0.f) ? sc : 0.2f * sc;
    escore[e] = sc;
    slot[e] = atomicAdd(&cnt[row], 1);
}

// ---------------- segment allocation (unordered, contiguous per row)
__global__ void kalloc_kernel(const int* __restrict__ cnt, int* __restrict__ ofs,
                              int* __restrict__ counter, int N) {
    int n = blockIdx.x * blockDim.x + threadIdx.x;
    if (n < N) ofs[n] = atomicAdd(counter, cnt[n]);
}

// ---------------- place perm-ordered edge records: packed offset + score
__global__ void kplace2_kernel(const int* __restrict__ eidx, const int* __restrict__ etype,
                               const float* __restrict__ escore,
                               const int* __restrict__ ofs, const int* __restrict__ slot,
                               unsigned* __restrict__ poff, float* __restrict__ pscore,
                               int N, int E) {
    int e = blockIdx.x * blockDim.x + threadIdx.x;
    if (e >= E) return;
    int row = eidx[e];
    int col = eidx[E + e];
    int r = etype[e];
    int pos = ofs[row] + slot[e];
    poff[pos] = (((unsigned)(r * N + col)) << 2) | (unsigned)r;
    pscore[pos] = escore[e];
}

// ---------------- 4 rows per block (one wave each): in-register softmax + gather
__global__ void __launch_bounds__(256)
krow2_kernel(const unsigned* __restrict__ poff, const float* __restrict__ pscore,
             const int* __restrict__ ofs, const int* __restrict__ cnt,
             const __hip_bfloat16* __restrict__ Hall,
             float* __restrict__ out, int N) {
    const int wave = threadIdx.x >> 6;
    const int lane = threadIdx.x & 63;
    const int n = blockIdx.x * 4 + wave;
    if (n >= N) return;
    const int start = ofs[n];
    const int deg = cnt[n];

    float acc0 = 0.f, acc1 = 0.f;

    if (deg <= 64) {
        float sc = -1e30f;
        unsigned u = 0u;
        int r_i = 0;
        if (lane < deg) {
            u = poff[start + lane];
            sc = pscore[start + lane];
            r_i = (int)(u & 3u);
        }
        float m0, m1, m2, m3;
        {
            float v0 = (r_i == 0 && lane < deg) ? sc : -1e30f;
            float v1 = (r_i == 1 && lane < deg) ? sc : -1e30f;
            float v2 = (r_i == 2 && lane < deg) ? sc : -1e30f;
            float v3 = (r_i == 3 && lane < deg) ? sc : -1e30f;
            #pragma unroll
            for (int o = 32; o > 0; o >>= 1) {
                v0 = fmaxf(v0, __shfl_xor(v0, o));
                v1 = fmaxf(v1, __shfl_xor(v1, o));
                v2 = fmaxf(v2, __shfl_xor(v2, o));
                v3 = fmaxf(v3, __shfl_xor(v3, o));
            }
            m0 = v0; m1 = v1; m2 = v2; m3 = v3;
        }
        float m_i = (r_i == 0) ? m0 : ((r_i == 1) ? m1 : ((r_i == 2) ? m2 : m3));
        float wgt = (lane < deg) ? __expf(sc - m_i) : 0.f;
        float s0, s1, s2, s3;
        {
            float v0 = (r_i == 0) ? wgt : 0.f;
            float v1 = (r_i == 1) ? wgt : 0.f;
            float v2 = (r_i == 2) ? wgt : 0.f;
            float v3 = (r_i == 3) ? wgt : 0.f;
            #pragma unroll
            for (int o = 32; o > 0; o >>= 1) {
                v0 += __shfl_xor(v0, o);
                v1 += __shfl_xor(v1, o);
                v2 += __shfl_xor(v2, o);
                v3 += __shfl_xor(v3, o);
            }
            s0 = v0; s1 = v1; s2 = v2; s3 = v3;
        }
        float s_i = (r_i == 0) ? s0 : ((r_i == 1) ? s1 : ((r_i == 2) ? s2 : s3));
        float alpha = (lane < deg && s_i > 0.f) ? (wgt / s_i) : 0.f;

        for (int j = 0; j < deg; j += 4) {
            #pragma unroll
            for (int jj = 0; jj < 4; ++jj) {
                int idx = j + jj;
                float al = __shfl(alpha, idx);
                int uj = __shfl((int)u, idx);
                if (idx < deg) {
                    const __hip_bfloat16* hp = Hall + (size_t)(((unsigned)uj) >> 2) * H_DIM;
                    acc0 += al * __bfloat162float(hp[lane]);
                    acc1 += al * __bfloat162float(hp[lane + 64]);
                }
            }
        }
    } else {
        float v0 = -1e30f, v1 = -1e30f, v2 = -1e30f, v3 = -1e30f;
        for (int i = lane; i < deg; i += 64) {
            unsigned u = poff[start + i];
            float sc = pscore[start + i];
            int r = (int)(u & 3u);
            if (r == 0) v0 = fmaxf(v0, sc);
            else if (r == 1) v1 = fmaxf(v1, sc);
            else if (r == 2) v2 = fmaxf(v2, sc);
            else v3 = fmaxf(v3, sc);
        }
        #pragma unroll
        for (int o = 32; o > 0; o >>= 1) {
            v0 = fmaxf(v0, __shfl_xor(v0, o));
            v1 = fmaxf(v1, __shfl_xor(v1, o));
            v2 = fmaxf(v2, __shfl_xor(v2, o));
            v3 = fmaxf(v3, __shfl_xor(v3, o));
        }
        const float m0 = v0, m1 = v1, m2 = v2, m3 = v3;
        float t0 = 0.f, t1 = 0.f, t2 = 0.f, t3 = 0.f;
        for (int i = lane; i < deg; i += 64) {
            unsigned u = poff[start + i];
            float sc = pscore[start + i];
            int r = (int)(u & 3u);
            if (r == 0) t0 += __expf(sc - m0);
            else if (r == 1) t1 += __expf(sc - m1);
            else if (r == 2) t2 += __expf(sc - m2);
            else t3 += __expf(sc - m3);
        }
        #pragma unroll
        for (int o = 32; o > 0; o >>= 1) {
            t0 += __shfl_xor(t0, o);
            t1 += __shfl_xor(t1, o);
            t2 += __shfl_xor(t2, o);
            t3 += __shfl_xor(t3, o);
        }
        float i0 = (t0 > 0.f) ? 1.f / t0 : 0.f;
        float i1 = (t1 > 0.f) ? 1.f / t1 : 0.f;
        float i2 = (t2 > 0.f) ? 1.f / t2 : 0.f;
        float i3 = (t3 > 0.f) ? 1.f / t3 : 0.f;
        for (int i = 0; i < deg; ++i) {
            unsigned u = poff[start + i];
            float sc = pscore[start + i];
            int r = (int)(u & 3u);
            float m_r = (r == 0) ? m0 : ((r == 1) ? m1 : ((r == 2) ? m2 : m3));
            float inv = (r == 0) ? i0 : ((r == 1) ? i1 : ((r == 2) ? i2 : i3));
            float al = __expf(sc - m_r) * inv;
            const __hip_bfloat16* hp = Hall + (size_t)(u >> 2) * H_DIM;
            acc0 += al * __bfloat162float(hp[lane]);
            acc1 += al * __bfloat162float(hp[lane + 64]);
        }
    }

    out[(size_t)n * H_DIM + lane] = acc0;
    out[(size_t)n * H_DIM + 64 + lane] = acc1;
}

// ---------------- launch
static inline char* carve(char*& p, size_t bytes) {
    char* q = p;
    p += (bytes + 255) & ~(size_t)255;
    return q;
}

extern "C" void kernel_launch(void* const* d_in, const int* in_sizes, int n_in,
                              void* d_out, int out_size, void* d_ws, size_t ws_size,
                              hipStream_t stream) {
    const float* x     = (const float*)d_in[0];
    const int*   eidx  = (const int*)d_in[1];
    const int*   etype = (const int*)d_in[2];
    const float* a     = (const float*)d_in[3];
    const float* W     = (const float*)d_in[4];
    const float* b     = (const float*)d_in[5];
    float* out = (float*)d_out;

    const int E = in_sizes[2];
    const int N = in_sizes[0] / D_DIM;

    char* p = (char*)d_ws;
    __hip_bfloat16* Hall = (__hip_bfloat16*)carve(p, (size_t)R_DIM * N * H_DIM * 2);
    unsigned short* xb   = (unsigned short*)carve(p, (size_t)N * D_DIM * 2);
    unsigned short* Wt   = (unsigned short*)carve(p, (size_t)R_DIM * D_DIM * H_DIM * 2);
    float* s1     = (float*)carve(p, (size_t)R_DIM * N * 4);
    float* s2     = (float*)carve(p, (size_t)R_DIM * N * 4);
    float* v1     = (float*)carve(p, R_DIM * D_DIM * 4);
    float* v2     = (float*)carve(p, R_DIM * D_DIM * 4);
    float* c1     = (float*)carve(p, 64);
    float* c2     = (float*)carve(p, 64);
    float* escore = (float*)carve(p, (size_t)E * 4);
    int*   slot   = (int*)carve(p, (size_t)E * 4);
    unsigned* poff   = (unsigned*)carve(p, (size_t)E * 4);
    float*    pscore = (float*)carve(p, (size_t)E * 4);
    int*   ofs    = (int*)carve(p, (size_t)N * 4);
    int*   cnt    = (int*)carve(p, (size_t)N * 4 + 4);   // counter lives at cnt[N]
    int*   counter = cnt + N;

    hipMemsetAsync(cnt, 0, (size_t)N * 4 + 4, stream);

    kv_kernel<<<4, 256, 0, stream>>>(W, b, a, v1, v2, c1, c2);
    wtcvt_kernel<<<(R_DIM * D_DIM * H_DIM + 255) / 256, 256, 0, stream>>>(W, Wt);
    ks2_kernel<<<(N + 7) / 8, 512, 0, stream>>>(x, v1, v2, c1, c2, s1, s2, xb, N);
    gemm_mfma3_kernel<<<(N + 127) / 128, 512, 0, stream>>>(xb, Wt, b, Hall, N);
    kscore_kernel<<<(E + 255) / 256, 256, 0, stream>>>(eidx, etype, s1, s2, escore, slot, cnt, N, E);
    kalloc_kernel<<<(N + 255) / 256, 256, 0, stream>>>(cnt, ofs, counter, N);
    kplace2_kernel<<<(E + 255) / 256, 256, 0, stream>>>(eidx, etype, escore, ofs, slot, poff, pscore, N, E);
    krow2_kernel<<<(N + 3) / 4, 256, 0, stream>>>(poff, pscore, ofs, cnt, Hall, out, N);
}

// Round 6
// 202.559 us; speedup vs baseline: 1.2629x; 1.0454x over previous
//
#include <hip/hip_runtime.h>
#include <hip/hip_bf16.h>

#define D_DIM 256
#define H_DIM 128
#define R_DIM 4

typedef __bf16 bf16x8 __attribute__((ext_vector_type(8)));
typedef float f32x4 __attribute__((ext_vector_type(4)));

__device__ __forceinline__ unsigned short f2bf(float f) {
    union { float f; unsigned u; } v; v.f = f;
    unsigned r = (v.u + 0x7FFFu + ((v.u >> 16) & 1u)) >> 16;   // RNE
    return (unsigned short)r;
}
__device__ __forceinline__ float bflo(unsigned v) {
    union { unsigned u; float f; } w; w.u = v << 16; return w.f;
}
__device__ __forceinline__ float bfhi(unsigned v) {
    union { unsigned u; float f; } w; w.u = v & 0xFFFF0000u; return w.f;
}

// ---------------- K_v: v1[r][d] = sum_h W[r][d][h]*a1[h]; v2 with a2; c1[r]=b[r].a1, c2[r]=b[r].a2
__global__ void kv_kernel(const float* __restrict__ W, const float* __restrict__ b,
                          const float* __restrict__ a,
                          float* __restrict__ v1, float* __restrict__ v2,
                          float* __restrict__ c1, float* __restrict__ c2) {
    int t = blockIdx.x * blockDim.x + threadIdx.x;
    if (t < R_DIM * D_DIM) {
        int r = t >> 8;
        int d = t & 255;
        const float* wp = W + ((size_t)r * D_DIM + d) * H_DIM;
        float acc1 = 0.f, acc2 = 0.f;
        for (int h = 0; h < H_DIM; ++h) {
            float w = wp[h];
            acc1 += w * a[h];
            acc2 += w * a[H_DIM + h];
        }
        v1[t] = acc1; v2[t] = acc2;
    }
    if (t < R_DIM) {
        const float* bp = b + t * H_DIM;
        float acc1 = 0.f, acc2 = 0.f;
        for (int h = 0; h < H_DIM; ++h) {
            acc1 += bp[h] * a[h];
            acc2 += bp[h] * a[H_DIM + h];
        }
        c1[t] = acc1; c2[t] = acc2;
    }
}

// ---------------- W (R,256,128) fp32 -> Wt (R,128,256) bf16 (transposed, K-contiguous)
__global__ void wtcvt_kernel(const float* __restrict__ W, unsigned short* __restrict__ Wt) {
    int idx = blockIdx.x * blockDim.x + threadIdx.x;
    if (idx >= R_DIM * D_DIM * H_DIM) return;
    int d = idx & 255;
    int h = (idx >> 8) & 127;
    int r = idx >> 15;
    Wt[idx] = f2bf(W[((size_t)(r * D_DIM + d)) * H_DIM + h]);
}

// ---------------- ks2: fused scores + x->bf16. One wave per row (coalesced 1KB row read).
__global__ void __launch_bounds__(512)
ks2_kernel(const float* __restrict__ x,
           const float* __restrict__ v1, const float* __restrict__ v2,
           const float* __restrict__ c1, const float* __restrict__ c2,
           float* __restrict__ s1, float* __restrict__ s2,
           unsigned short* __restrict__ xb, int N) {
    __shared__ float sv1[R_DIM * D_DIM];
    __shared__ float sv2[R_DIM * D_DIM];
    __shared__ float sc[8];
    const int t = threadIdx.x;
    for (int i = t; i < R_DIM * D_DIM; i += 512) { sv1[i] = v1[i]; sv2[i] = v2[i]; }
    if (t < 4) { sc[t] = c1[t]; sc[4 + t] = c2[t]; }
    __syncthreads();
    const int wave = t >> 6, lane = t & 63;
    const int n = blockIdx.x * 8 + wave;
    if (n >= N) return;
    float4 xv = *(const float4*)(x + (size_t)n * D_DIM + lane * 4);
    unsigned lo = (unsigned)f2bf(xv.x) | ((unsigned)f2bf(xv.y) << 16);
    unsigned hi = (unsigned)f2bf(xv.z) | ((unsigned)f2bf(xv.w) << 16);
    *(uint2*)(xb + (size_t)n * D_DIM + lane * 4) = make_uint2(lo, hi);
    float d0, d1, d2, d3, d4, d5, d6, d7;
    {
        float4 w;
        w = *(const float4*)&sv1[0 * D_DIM + lane * 4]; d0 = xv.x*w.x + xv.y*w.y + xv.z*w.z + xv.w*w.w;
        w = *(const float4*)&sv1[1 * D_DIM + lane * 4]; d1 = xv.x*w.x + xv.y*w.y + xv.z*w.z + xv.w*w.w;
        w = *(const float4*)&sv1[2 * D_DIM + lane * 4]; d2 = xv.x*w.x + xv.y*w.y + xv.z*w.z + xv.w*w.w;
        w = *(const float4*)&sv1[3 * D_DIM + lane * 4]; d3 = xv.x*w.x + xv.y*w.y + xv.z*w.z + xv.w*w.w;
        w = *(const float4*)&sv2[0 * D_DIM + lane * 4]; d4 = xv.x*w.x + xv.y*w.y + xv.z*w.z + xv.w*w.w;
        w = *(const float4*)&sv2[1 * D_DIM + lane * 4]; d5 = xv.x*w.x + xv.y*w.y + xv.z*w.z + xv.w*w.w;
        w = *(const float4*)&sv2[2 * D_DIM + lane * 4]; d6 = xv.x*w.x + xv.y*w.y + xv.z*w.z + xv.w*w.w;
        w = *(const float4*)&sv2[3 * D_DIM + lane * 4]; d7 = xv.x*w.x + xv.y*w.y + xv.z*w.z + xv.w*w.w;
    }
    #pragma unroll
    for (int o = 32; o > 0; o >>= 1) {
        d0 += __shfl_xor(d0, o); d1 += __shfl_xor(d1, o);
        d2 += __shfl_xor(d2, o); d3 += __shfl_xor(d3, o);
        d4 += __shfl_xor(d4, o); d5 += __shfl_xor(d5, o);
        d6 += __shfl_xor(d6, o); d7 += __shfl_xor(d7, o);
    }
    if (lane == 0) {
        s1[(size_t)0 * N + n] = d0 + sc[0];
        s1[(size_t)1 * N + n] = d1 + sc[1];
        s1[(size_t)2 * N + n] = d2 + sc[2];
        s1[(size_t)3 * N + n] = d3 + sc[3];
        s2[(size_t)0 * N + n] = d4 + sc[4];
        s2[(size_t)1 * N + n] = d5 + sc[5];
        s2[(size_t)2 * N + n] = d6 + sc[6];
        s2[(size_t)3 * N + n] = d7 + sc[7];
    }
}

// ---------------- MFMA GEMM v3 (unchanged from round 5)
#define A_BYTES (128 * 512)
#define BSLOT_BYTES (128 * 64)
__global__ void __launch_bounds__(512)
gemm_mfma3_kernel(const unsigned short* __restrict__ xb, const unsigned short* __restrict__ Wt,
                  const float* __restrict__ bias, __hip_bfloat16* __restrict__ Hall, int N) {
    __shared__ __align__(16) char lds[A_BYTES + 2 * BSLOT_BYTES];   // 80 KB

    const int t = threadIdx.x;
    const int lane = t & 63;
    const int w = t >> 6;
    const int wm = w >> 2;
    const int wn = w & 3;
    const int q = lane >> 4;
    const int l15 = lane & 15;
    const int nBase = blockIdx.x * 128;
    const int hB = t >> 2, hCh = t & 3;

    uint4 aR[8];
    #pragma unroll
    for (int i = 0; i < 8; ++i) {
        int idx = i * 512 + t;
        int n = idx >> 5, ch = idx & 31;
        int gn = nBase + n; if (gn >= N) gn = N - 1;
        aR[i] = *(const uint4*)(xb + (size_t)gn * D_DIM + ch * 8);
    }
    uint4 bR = *(const uint4*)(Wt + (size_t)hB * D_DIM + hCh * 8);
    #pragma unroll
    for (int i = 0; i < 8; ++i) {
        int idx = i * 512 + t;
        int n = idx >> 5, ch = idx & 31;
        *(uint4*)(lds + n * 512 + ((ch ^ (n & 7)) << 4)) = aR[i];
    }
    *(uint4*)(lds + A_BYTES + hB * 64 + ((hCh ^ ((hB >> 1) & 3)) << 4)) = bR;
    __syncthreads();

    f32x4 acc[2][4];
    {
        #pragma unroll
        for (int hf = 0; hf < 2; ++hf) {
            f32x4 bv = *(const f32x4*)(bias + 0 * H_DIM + wn * 32 + hf * 16 + q * 4);
            #pragma unroll
            for (int nf = 0; nf < 4; ++nf) acc[hf][nf] = bv;
        }
    }

    int cur = 0;
    #pragma unroll 1
    for (int c = 0; c < 32; ++c) {
        const int r = c >> 3;
        uint4 nb;
        if (c < 31) {
            int cn = c + 1;
            nb = *(const uint4*)(Wt + ((size_t)((cn >> 3) * H_DIM + hB)) * D_DIM + (cn & 7) * 32 + hCh * 8);
        }
        bf16x8 wf[2], xf[4];
        #pragma unroll
        for (int hf = 0; hf < 2; ++hf) {
            int hl = wn * 32 + hf * 16 + l15;
            wf[hf] = *(const bf16x8*)(lds + A_BYTES + (cur ? BSLOT_BYTES : 0) + hl * 64 + ((q ^ ((hl >> 1) & 3)) << 4));
        }
        #pragma unroll
        for (int nf = 0; nf < 4; ++nf) {
            int nl = wm * 64 + nf * 16 + l15;
            int sA = ((c & 7) << 2) | q;
            xf[nf] = *(const bf16x8*)(lds + nl * 512 + ((sA ^ (nl & 7)) << 4));
        }
        #pragma unroll
        for (int hf = 0; hf < 2; ++hf)
            #pragma unroll
            for (int nf = 0; nf < 4; ++nf)
                acc[hf][nf] = __builtin_amdgcn_mfma_f32_16x16x32_bf16(wf[hf], xf[nf], acc[hf][nf], 0, 0, 0);
        if (c < 31)
            *(uint4*)(lds + A_BYTES + (cur ? 0 : BSLOT_BYTES) + hB * 64 + ((hCh ^ ((hB >> 1) & 3)) << 4)) = nb;
        __syncthreads();
        cur ^= 1;
        if ((c & 7) == 7) {
            #pragma unroll
            for (int hf = 0; hf < 2; ++hf) {
                int h = wn * 32 + hf * 16 + q * 4;
                #pragma unroll
                for (int nf = 0; nf < 4; ++nf) {
                    int n = nBase + wm * 64 + nf * 16 + l15;
                    if (n < N) {
                        unsigned lo = (unsigned)f2bf(acc[hf][nf][0]) | ((unsigned)f2bf(acc[hf][nf][1]) << 16);
                        unsigned hi = (unsigned)f2bf(acc[hf][nf][2]) | ((unsigned)f2bf(acc[hf][nf][3]) << 16);
                        *(uint2*)((unsigned short*)Hall + ((size_t)r * N + n) * H_DIM + h) = make_uint2(lo, hi);
                    }
                }
            }
            if (c < 31) {
                #pragma unroll
                for (int hf = 0; hf < 2; ++hf) {
                    f32x4 bv = *(const f32x4*)(bias + (r + 1) * H_DIM + wn * 32 + hf * 16 + q * 4);
                    #pragma unroll
                    for (int nf = 0; nf < 4; ++nf) acc[hf][nf] = bv;
                }
            }
        }
    }
}

// ---------------- kcount: per-row slot assignment only
__global__ void kcount_kernel(const int* __restrict__ eidx, int* __restrict__ slot,
                              int* __restrict__ cnt, int E) {
    int e = blockIdx.x * blockDim.x + threadIdx.x;
    if (e >= E) return;
    slot[e] = atomicAdd(&cnt[eidx[e]], 1);
}

// ---------------- segment allocation (unordered, contiguous per row)
__global__ void kalloc_kernel(const int* __restrict__ cnt, int* __restrict__ ofs,
                              int* __restrict__ counter, int N) {
    int n = blockIdx.x * blockDim.x + threadIdx.x;
    if (n < N) ofs[n] = atomicAdd(counter, cnt[n]);
}

// ---------------- kplace: compute score inline + place perm-ordered records
__global__ void kplace3_kernel(const int* __restrict__ eidx, const int* __restrict__ etype,
                               const float* __restrict__ s1, const float* __restrict__ s2,
                               const int* __restrict__ ofs, const int* __restrict__ slot,
                               unsigned* __restrict__ poff, float* __restrict__ pscore,
                               int N, int E) {
    int e = blockIdx.x * blockDim.x + threadIdx.x;
    if (e >= E) return;
    int row = eidx[e];
    int col = eidx[E + e];
    int r = etype[e];
    float sc = s1[(size_t)r * N + row] + s2[(size_t)r * N + col];
    sc = (sc >= 0.f) ? sc : 0.2f * sc;
    int pos = ofs[row] + slot[e];
    poff[pos] = (((unsigned)(r * N + col)) << 2) | (unsigned)r;
    pscore[pos] = sc;
}

// ---------------- krow3: 4 rows/block; softmax in-register; full-row 256B gather per edge,
// chunk-16 prefetch into static register arrays; float2 packed output.
__global__ void __launch_bounds__(256)
krow3_kernel(const unsigned* __restrict__ poff, const float* __restrict__ pscore,
             const int* __restrict__ ofs, const int* __restrict__ cnt,
             const __hip_bfloat16* __restrict__ Hall,
             float* __restrict__ out, int N) {
    const int wave = threadIdx.x >> 6;
    const int lane = threadIdx.x & 63;
    const int n = blockIdx.x * 4 + wave;
    if (n >= N) return;
    const int start = ofs[n];
    const int deg = cnt[n];

    float accL = 0.f, accH = 0.f;
    const unsigned* hp0 = (const unsigned*)Hall + lane;   // +row*64 per edge

    if (deg <= 64) {
        // ---- each lane owns one edge
        float sc = -1e30f;
        unsigned u = 0u;
        int r_i = 0;
        if (lane < deg) {
            u = poff[start + lane];
            sc = pscore[start + lane];
            r_i = (int)(u & 3u);
        }
        float m0, m1, m2, m3;
        {
            float v0 = (r_i == 0 && lane < deg) ? sc : -1e30f;
            float v1 = (r_i == 1 && lane < deg) ? sc : -1e30f;
            float v2 = (r_i == 2 && lane < deg) ? sc : -1e30f;
            float v3 = (r_i == 3 && lane < deg) ? sc : -1e30f;
            #pragma unroll
            for (int o = 32; o > 0; o >>= 1) {
                v0 = fmaxf(v0, __shfl_xor(v0, o));
                v1 = fmaxf(v1, __shfl_xor(v1, o));
                v2 = fmaxf(v2, __shfl_xor(v2, o));
                v3 = fmaxf(v3, __shfl_xor(v3, o));
            }
            m0 = v0; m1 = v1; m2 = v2; m3 = v3;
        }
        float m_i = (r_i == 0) ? m0 : ((r_i == 1) ? m1 : ((r_i == 2) ? m2 : m3));
        float wgt = (lane < deg) ? __expf(sc - m_i) : 0.f;
        float s0, s1, s2, s3;
        {
            float v0 = (r_i == 0) ? wgt : 0.f;
            float v1 = (r_i == 1) ? wgt : 0.f;
            float v2 = (r_i == 2) ? wgt : 0.f;
            float v3 = (r_i == 3) ? wgt : 0.f;
            #pragma unroll
            for (int o = 32; o > 0; o >>= 1) {
                v0 += __shfl_xor(v0, o);
                v1 += __shfl_xor(v1, o);
                v2 += __shfl_xor(v2, o);
                v3 += __shfl_xor(v3, o);
            }
            s0 = v0; s1 = v1; s2 = v2; s3 = v3;
        }
        float s_i = (r_i == 0) ? s0 : ((r_i == 1) ? s1 : ((r_i == 2) ? s2 : s3));
        float alpha = (lane < deg && s_i > 0.f) ? (wgt / s_i) : 0.f;

        // ---- pass 3: chunk-16 prefetch; idx>=deg lanes carry u=0/alpha=0 (safe dummy)
        for (int chunk = 0; chunk < deg; chunk += 16) {
            unsigned vals[16];
            float als[16];
            #pragma unroll
            for (int jj = 0; jj < 16; ++jj) {
                int idx = chunk + jj;
                unsigned uj = (unsigned)__shfl((int)u, idx);
                als[jj] = __shfl(alpha, idx);
                vals[jj] = hp0[(size_t)(uj >> 2) * 64];
            }
            #pragma unroll
            for (int jj = 0; jj < 16; ++jj) {
                accL += als[jj] * bflo(vals[jj]);
                accH += als[jj] * bfhi(vals[jj]);
            }
        }
    } else {
        // ---- rare fallback: deg > 64
        float v0 = -1e30f, v1 = -1e30f, v2 = -1e30f, v3 = -1e30f;
        for (int i = lane; i < deg; i += 64) {
            unsigned u = poff[start + i];
            float sc = pscore[start + i];
            int r = (int)(u & 3u);
            if (r == 0) v0 = fmaxf(v0, sc);
            else if (r == 1) v1 = fmaxf(v1, sc);
            else if (r == 2) v2 = fmaxf(v2, sc);
            else v3 = fmaxf(v3, sc);
        }
        #pragma unroll
        for (int o = 32; o > 0; o >>= 1) {
            v0 = fmaxf(v0, __shfl_xor(v0, o));
            v1 = fmaxf(v1, __shfl_xor(v1, o));
            v2 = fmaxf(v2, __shfl_xor(v2, o));
            v3 = fmaxf(v3, __shfl_xor(v3, o));
        }
        const float m0 = v0, m1 = v1, m2 = v2, m3 = v3;
        float t0 = 0.f, t1 = 0.f, t2 = 0.f, t3 = 0.f;
        for (int i = lane; i < deg; i += 64) {
            unsigned u = poff[start + i];
            float sc = pscore[start + i];
            int r = (int)(u & 3u);
            if (r == 0) t0 += __expf(sc - m0);
            else if (r == 1) t1 += __expf(sc - m1);
            else if (r == 2) t2 += __expf(sc - m2);
            else t3 += __expf(sc - m3);
        }
        #pragma unroll
        for (int o = 32; o > 0; o >>= 1) {
            t0 += __shfl_xor(t0, o);
            t1 += __shfl_xor(t1, o);
            t2 += __shfl_xor(t2, o);
            t3 += __shfl_xor(t3, o);
        }
        float i0 = (t0 > 0.f) ? 1.f / t0 : 0.f;
        float i1 = (t1 > 0.f) ? 1.f / t1 : 0.f;
        float i2 = (t2 > 0.f) ? 1.f / t2 : 0.f;
        float i3 = (t3 > 0.f) ? 1.f / t3 : 0.f;
        for (int i = 0; i < deg; ++i) {
            unsigned u = poff[start + i];
            float sc = pscore[start + i];
            int r = (int)(u & 3u);
            float m_r = (r == 0) ? m0 : ((r == 1) ? m1 : ((r == 2) ? m2 : m3));
            float inv = (r == 0) ? i0 : ((r == 1) ? i1 : ((r == 2) ? i2 : i3));
            float al = __expf(sc - m_r) * inv;
            unsigned v = hp0[(size_t)(u >> 2) * 64];
            accL += al * bflo(v);
            accH += al * bfhi(v);
        }
    }

    *(float2*)(out + (size_t)n * H_DIM + 2 * lane) = make_float2(accL, accH);
}

// ---------------- launch
static inline char* carve(char*& p, size_t bytes) {
    char* q = p;
    p += (bytes + 255) & ~(size_t)255;
    return q;
}

extern "C" void kernel_launch(void* const* d_in, const int* in_sizes, int n_in,
                              void* d_out, int out_size, void* d_ws, size_t ws_size,
                              hipStream_t stream) {
    const float* x     = (const float*)d_in[0];
    const int*   eidx  = (const int*)d_in[1];
    const int*   etype = (const int*)d_in[2];
    const float* a     = (const float*)d_in[3];
    const float* W     = (const float*)d_in[4];
    const float* b     = (const float*)d_in[5];
    float* out = (float*)d_out;

    const int E = in_sizes[2];
    const int N = in_sizes[0] / D_DIM;

    char* p = (char*)d_ws;
    __hip_bfloat16* Hall = (__hip_bfloat16*)carve(p, (size_t)R_DIM * N * H_DIM * 2);
    unsigned short* xb   = (unsigned short*)carve(p, (size_t)N * D_DIM * 2);
    unsigned short* Wt   = (unsigned short*)carve(p, (size_t)R_DIM * D_DIM * H_DIM * 2);
    float* s1     = (float*)carve(p, (size_t)R_DIM * N * 4);
    float* s2     = (float*)carve(p, (size_t)R_DIM * N * 4);
    float* v1     = (float*)carve(p, R_DIM * D_DIM * 4);
    float* v2     = (float*)carve(p, R_DIM * D_DIM * 4);
    float* c1     = (float*)carve(p, 64);
    float* c2     = (float*)carve(p, 64);
    int*   slot   = (int*)carve(p, (size_t)E * 4);
    unsigned* poff   = (unsigned*)carve(p, (size_t)E * 4);
    float*    pscore = (float*)carve(p, (size_t)E * 4);
    int*   ofs    = (int*)carve(p, (size_t)N * 4);
    int*   cnt    = (int*)carve(p, (size_t)N * 4 + 4);   // counter lives at cnt[N]
    int*   counter = cnt + N;

    hipMemsetAsync(cnt, 0, (size_t)N * 4 + 4, stream);

    kv_kernel<<<4, 256, 0, stream>>>(W, b, a, v1, v2, c1, c2);
    wtcvt_kernel<<<(R_DIM * D_DIM * H_DIM + 255) / 256, 256, 0, stream>>>(W, Wt);
    ks2_kernel<<<(N + 7) / 8, 512, 0, stream>>>(x, v1, v2, c1, c2, s1, s2, xb, N);
    gemm_mfma3_kernel<<<(N + 127) / 128, 512, 0, stream>>>(xb, Wt, b, Hall, N);
    kcount_kernel<<<(E + 255) / 256, 256, 0, stream>>>(eidx, slot, cnt, E);
    kalloc_kernel<<<(N + 255) / 256, 256, 0, stream>>>(cnt, ofs, counter, N);
    kplace3_kernel<<<(E + 255) / 256, 256, 0, stream>>>(eidx, etype, s1, s2, ofs, slot, poff, pscore, N, E);
    krow3_kernel<<<(N + 3) / 4, 256, 0, stream>>>(poff, pscore, ofs, cnt, Hall, out, N);
}